// Round 7
// baseline (428.360 us; speedup 1.0000x reference)
//
#include <hip/hip_runtime.h>
#include <hip/hip_bf16.h>

typedef __attribute__((ext_vector_type(4))) float f32x4;
typedef __attribute__((ext_vector_type(8))) __bf16 bf16x8;
typedef __attribute__((ext_vector_type(4))) unsigned int u32x4;

// B=32, S=4096, E=A=512.
// out = [weighted (32*512), prob (32*4096)] fp32, total 147456.

__device__ __forceinline__ float lo_bf(unsigned int u) {
  return __builtin_bit_cast(float, u << 16);
}
__device__ __forceinline__ float hi_bf(unsigned int u) {
  return __builtin_bit_cast(float, u & 0xffff0000u);
}

// Raw barrier: drain LDS ops only — vmcnt (global loads/stores) stays in flight.
__device__ __forceinline__ void barrier_lgkm() {
  asm volatile("s_waitcnt lgkmcnt(0)" ::: "memory");
  __builtin_amdgcn_s_barrier();
  asm volatile("" ::: "memory");
}

// ---------- prep 1: fragment-ordered bf16 W_enc^T ----------
// Wf[((nt*16 + kb)*64 + lane)*8 + j] = bf16(W_enc[kb*32 + (lane>>4)*8 + j][nt*16 + (lane&15)])
__global__ void prep_w(const float* __restrict__ W_enc, unsigned short* __restrict__ Wf) {
  int idx = blockIdx.x * 256 + threadIdx.x;   // 0..32767
  int lane = idx & 63;
  int grp = idx >> 6;                         // nt*16 + kb
  int nt = grp >> 4, kb = grp & 15;
  int n = nt * 16 + (lane & 15);
  int k0 = kb * 32 + (lane >> 4) * 8;
  unsigned short* dst = Wf + idx * 8;
  #pragma unroll
  for (int j = 0; j < 8; ++j) {
    float f = W_enc[(k0 + j) * 512 + n];
    dst[j] = __builtin_bit_cast(unsigned short, (__bf16)f);
  }
}

// ---------- prep 2 (k-split x4): cpart[j][b][a] = partial dec_h@W_dec (+biases in j==0) ----------
__global__ void prep_c(const float* __restrict__ dec_h, const float* __restrict__ W_dec,
                       const float* __restrict__ b_dec, const float* __restrict__ b_enc,
                       float* __restrict__ cpart) {
  int b = blockIdx.x >> 2, j = blockIdx.x & 3;
  int a = threadIdx.x;                        // 512 threads
  const float* dh = dec_h + b * 512 + j * 128;
  const float* wd = W_dec + (j * 128) * 512 + a;
  float s = (j == 0) ? (b_dec[a] + b_enc[a]) : 0.f;
  #pragma unroll 8
  for (int k = 0; k < 128; ++k) s += dh[k] * wd[k * 512];
  cpart[j * 16384 + b * 512 + a] = s;
}

// ---------- main: 1024 thr / 16 waves / 1 block/CU. Waves 0-7 compute; waves 8-15
// ---------- stage + softmax + pw, one barrier per window, 10 windows of 8 chunks. ----------
__global__ __launch_bounds__(1024, 4) void attn_main(
    const float* __restrict__ input, const unsigned short* __restrict__ Wf,
    const float* __restrict__ cpart, const float* __restrict__ w_att,
    float* __restrict__ att_out, float* __restrict__ m_out, float* __restrict__ pw_out) {
  __shared__ u32x4 A4[8192];                 // 2 x (64 rows x 512 bf16), XOR-swizzled (128 KB)
  __shared__ float c_lds[512];
  __shared__ float w_lds[512];
  __shared__ float red[2][8][64];            // per-window epilogue partials (double-buffered)
  __shared__ float redf[2][512];             // pw accumulators (double-buffered, atomicAdd)

  char* Al = (char*)A4;
  const int tid = threadIdx.x;
  const int wave = tid >> 6, lane = tid & 63;
  const int l15 = lane & 15, l4 = lane >> 4;
  const int blk = blockIdx.x;                // 256 blocks, 1 per CU
  const int ci0 = blk * 8;                   // 8 chunks of 64 rows per block
  const int b = ci0 >> 6;                    // batch (all 8 chunks in same batch)
  const bool is_stage = wave >= 8;
  const int st = tid & 511;                  // stage thread id 0..511
  const int srow0 = st >> 6;                 // stage base row 0..7
  const int sc32 = st & 63;                  // stage col unit

  float4 g[8][2];                            // in-flight staging regs (64 VGPR, stage waves)

  auto ISSUE = [&](int ci) {                 // issue 16 global 16B loads, no waiting
    const float* base = input + (long)ci * 32768;
    #pragma unroll
    for (int j = 0; j < 8; ++j) {
      const float4* s4 = (const float4*)(base + (srow0 + j * 8) * 512 + sc32 * 8);
      g[j][0] = s4[0];
      g[j][1] = s4[1];
    }
  };
  auto COMMIT = [&](int bufsel) {            // cvt + swizzled LDS write (drains vmcnt)
    char* dst = Al + bufsel * 65536;
    #pragma unroll
    for (int j = 0; j < 8; ++j) {
      int row = srow0 + j * 8;
      bf16x8 v;
      v[0] = (__bf16)g[j][0].x; v[1] = (__bf16)g[j][0].y;
      v[2] = (__bf16)g[j][0].z; v[3] = (__bf16)g[j][0].w;
      v[4] = (__bf16)g[j][1].x; v[5] = (__bf16)g[j][1].y;
      v[6] = (__bf16)g[j][1].z; v[7] = (__bf16)g[j][1].w;
      *(bf16x8*)(dst + row * 1024 + ((sc32 * 16) ^ ((row & 7) << 4))) = v;
    }
  };

  // ---- prologue ----
  if (!is_stage) {
    c_lds[tid] = cpart[b * 512 + tid] + cpart[16384 + b * 512 + tid]
               + cpart[32768 + b * 512 + tid] + cpart[49152 + b * 512 + tid];
    w_lds[tid] = w_att[tid];
  } else {
    redf[0][st] = 0.f;
    redf[1][st] = 0.f;
    ISSUE(ci0);
    COMMIT(0);
  }
  barrier_lgkm();

  const bf16x8* Wfp = (const bf16x8*)Wf;

  for (int i = 0; i < 10; ++i) {
    if (!is_stage) {
      if (i < 8) {
        const char* Ab = Al + (i & 1) * 65536;
        // ---- K-loop: wave covers n-tiles wave*4 .. wave*4+3, rows 0..63 ----
        f32x4 acc[4][4];
        #pragma unroll
        for (int mi = 0; mi < 4; ++mi)
          #pragma unroll
          for (int nj = 0; nj < 4; ++nj) {
            f32x4 z = {0.f, 0.f, 0.f, 0.f};
            acc[mi][nj] = z;
          }
        const bf16x8* wb = Wfp + (wave * 64) * 64 + lane;   // wave's 4 ntiles x 16 kb
        bf16x8 bva[4], bvb[4];
        #pragma unroll
        for (int nj = 0; nj < 4; ++nj) bva[nj] = wb[(nj * 16) * 64];
        #pragma unroll
        for (int kb = 0; kb < 16; ++kb) {
          if (kb < 15) {
            #pragma unroll
            for (int nj = 0; nj < 4; ++nj) bvb[nj] = wb[(nj * 16 + kb + 1) * 64];
          }
          __builtin_amdgcn_s_setprio(1);
          #pragma unroll
          for (int mi = 0; mi < 4; ++mi) {
            int row = mi * 16 + l15;
            bf16x8 afr = *(const bf16x8*)(Ab + row * 1024 + (((kb * 64) + l4 * 16) ^ ((row & 7) << 4)));
            #pragma unroll
            for (int nj = 0; nj < 4; ++nj)
              acc[mi][nj] = __builtin_amdgcn_mfma_f32_16x16x32_bf16(afr, bva[nj], acc[mi][nj], 0, 0, 0);
          }
          __builtin_amdgcn_s_setprio(0);
          #pragma unroll
          for (int nj = 0; nj < 4; ++nj) bva[nj] = bvb[nj];
        }
        // ---- epilogue: attp[row] = sum_n relu(enc_att + c[n]) * w[n] ----
        float attp[16];
        #pragma unroll
        for (int q = 0; q < 16; ++q) attp[q] = 0.f;
        #pragma unroll
        for (int nj = 0; nj < 4; ++nj) {
          int n = (wave * 4 + nj) * 16 + l15;
          float cc = c_lds[n], ww = w_lds[n];
          #pragma unroll
          for (int mi = 0; mi < 4; ++mi)
            #pragma unroll
            for (int r = 0; r < 4; ++r)
              attp[mi * 4 + r] += fmaxf(acc[mi][nj][r] + cc, 0.f) * ww;
        }
        #pragma unroll
        for (int off = 1; off < 16; off <<= 1)
          #pragma unroll
          for (int q = 0; q < 16; ++q)
            attp[q] += __shfl_xor(attp[q], off, 64);
        if (l15 == 0) {
          #pragma unroll
          for (int mi = 0; mi < 4; ++mi)
            #pragma unroll
            for (int r = 0; r < 4; ++r)
              red[i & 1][wave][mi * 16 + l4 * 4 + r] = attp[mi * 4 + r];
        }
      }
      // windows 8,9: compute waves just hit the barrier
    } else {
      // ---- stage group: issue-early, then post-work for chunk i-1, then commit ----
      if (i < 7) ISSUE(ci0 + i + 1);

      if (i >= 2) {                          // store pw(chunk i-2), re-zero buffer
        int par = i & 1;                     // == (i-2)&1
        float v = redf[par][st];
        pw_out[(ci0 + i - 2) * 512 + st] = v;
        redf[par][st] = 0.f;
      }

      if (i >= 1 && i <= 8) {                // softmax(i-1) redundant + pw(i-1)
        const int ci = ci0 + i - 1;
        const int par = (i - 1) & 1;
        float av = 0.f;
        #pragma unroll
        for (int cw = 0; cw < 8; ++cw) av += red[par][cw][lane];
        float m = av;
        #pragma unroll
        for (int off = 32; off >= 1; off >>= 1) m = fmaxf(m, __shfl_xor(m, off, 64));
        float p = expf(av - m);
        if (wave == 8) {
          att_out[b * 4096 + (ci & 63) * 64 + lane] = av;  // b_att omitted: cancels in softmax
          if (lane == 0) m_out[ci] = m;
        }
        // pw: wave w reads ONLY rows s == (w-8) mod 8 — the rows it commits later.
        const char* Ab = Al + par * 65536;
        const int wr = wave - 8;
        float pw0[4], pw1[4];
        #pragma unroll
        for (int q = 0; q < 4; ++q) { pw0[q] = 0.f; pw1[q] = 0.f; }
        #pragma unroll
        for (int k = 0; k < 8; ++k) {
          int s = wr + k * 8;
          float ps = __shfl(p, s, 64);
          #pragma unroll
          for (int q = 0; q < 4; ++q) {
            int c = lane + q * 64;
            unsigned int u = *(const unsigned int*)(Ab + s * 1024 + ((c * 4) ^ ((s & 7) << 4)));
            pw0[q] += ps * lo_bf(u);
            pw1[q] += ps * hi_bf(u);
          }
        }
        #pragma unroll
        for (int q = 0; q < 4; ++q) {
          int c = lane + q * 64;
          atomicAdd(&redf[par][c * 2], pw0[q]);
          atomicAdd(&redf[par][c * 2 + 1], pw1[q]);
        }
      }

      asm volatile("" ::: "memory");         // keep pw reads before commit writes
      if (i < 7) COMMIT((i + 1) & 1);
    }
    barrier_lgkm();
  }
}

// ---------- finalize: per-batch global softmax + rescaled partial-sum reduction ----------
__global__ void finalize(const float* __restrict__ att, const float* __restrict__ m_blk,
                         const float* __restrict__ pw, float* __restrict__ out) {
  const int bg = blockIdx.x;                 // 128 blocks = 32 b x 4 groups
  const int b = bg >> 2, g = bg & 3;
  const int tid = threadIdx.x;               // 256
  const int wave = tid >> 6, lane = tid & 63;
  __shared__ float wred[4];
  __shared__ float zred[4];
  __shared__ float fac[64];

  float v[16];
  float mx = -3.4e38f;
  #pragma unroll
  for (int i = 0; i < 16; ++i) {
    v[i] = att[b * 4096 + i * 256 + tid];
    mx = fmaxf(mx, v[i]);
  }
  #pragma unroll
  for (int off = 32; off >= 1; off >>= 1) mx = fmaxf(mx, __shfl_xor(mx, off, 64));
  if (lane == 0) wred[wave] = mx;
  __syncthreads();
  mx = fmaxf(fmaxf(wred[0], wred[1]), fmaxf(wred[2], wred[3]));

  float z = 0.f;
  #pragma unroll
  for (int i = 0; i < 16; ++i) { v[i] = expf(v[i] - mx); z += v[i]; }
  #pragma unroll
  for (int off = 32; off >= 1; off >>= 1) z += __shfl_xor(z, off, 64);
  if (lane == 0) zred[wave] = z;
  __syncthreads();
  z = zred[0] + zred[1] + zred[2] + zred[3];
  float invZ = 1.f / z;

  #pragma unroll
  for (int i = 0; i < 4; ++i) {
    int ii = g * 4 + i;
    out[16384 + b * 4096 + ii * 256 + tid] = v[ii] * invZ;   // prob (this block's quarter)
  }

  if (tid < 64) fac[tid] = expf(m_blk[b * 64 + tid] - mx) * invZ;
  __syncthreads();

  int col = g * 128 + (tid >> 1);
  int h = tid & 1;
  float w0 = 0.f;
  #pragma unroll 8
  for (int s = h * 32; s < h * 32 + 32; ++s)
    w0 += fac[s] * pw[(b * 64 + s) * 512 + col];
  w0 += __shfl_xor(w0, 1, 64);
  if (h == 0) out[b * 512 + col] = w0;                       // weighted
}

extern "C" void kernel_launch(void* const* d_in, const int* in_sizes, int n_in,
                              void* d_out, int out_size, void* d_ws, size_t ws_size,
                              hipStream_t stream) {
  const float* input = (const float*)d_in[0];
  const float* dec_h = (const float*)d_in[1];
  const float* W_enc = (const float*)d_in[2];
  const float* b_enc = (const float*)d_in[3];
  const float* W_dec = (const float*)d_in[4];
  const float* b_dec = (const float*)d_in[5];
  const float* w_att = (const float*)d_in[6];
  // d_in[7] = b_att: constant shift of logits, cancels in softmax.
  float* out = (float*)d_out;

  char* ws = (char*)d_ws;
  unsigned short* Wf = (unsigned short*)(ws);           // 512 KB  fragment-ordered bf16 W_enc^T
  float* cpart = (float*)(ws + 524288);                 // 256 KB  dec_att partials [4][32][512]
  float* att   = (float*)(ws + 786432);                 // 512 KB  logits [32][4096]
  float* m_b   = (float*)(ws + 1310720);                // 8 KB    per-chunk max [2048]
  float* pw    = (float*)(ws + 1318912);                // 4 MB    partial weighted [2048][512]

  hipLaunchKernelGGL(prep_w, dim3(128), dim3(256), 0, stream, W_enc, Wf);
  hipLaunchKernelGGL(prep_c, dim3(128), dim3(512), 0, stream, dec_h, W_dec, b_dec, b_enc, cpart);
  hipLaunchKernelGGL(attn_main, dim3(256), dim3(1024), 0, stream, input, Wf, cpart, w_att, att, m_b, pw);
  hipLaunchKernelGGL(finalize, dim3(128), dim3(256), 0, stream, att, m_b, pw, out);
}

// Round 8
// 129.029 us; speedup vs baseline: 3.3199x; 3.3199x over previous
//
#include <hip/hip_runtime.h>
#include <hip/hip_bf16.h>

typedef __attribute__((ext_vector_type(4))) float f32x4;
typedef __attribute__((ext_vector_type(8))) __bf16 bf16x8;
typedef __attribute__((ext_vector_type(4))) unsigned int u32x4;

// B=32, S=4096, E=A=512.
// out = [weighted (32*512), prob (32*4096)] fp32, total 147456.

__device__ __forceinline__ float lo_bf(unsigned int u) {
  return __builtin_bit_cast(float, u << 16);
}
__device__ __forceinline__ float hi_bf(unsigned int u) {
  return __builtin_bit_cast(float, u & 0xffff0000u);
}

// Raw barrier: drain LDS ops only — vmcnt (global loads/stores) stays in flight.
__device__ __forceinline__ void barrier_lgkm() {
  asm volatile("s_waitcnt lgkmcnt(0)" ::: "memory");
  __builtin_amdgcn_s_barrier();
  asm volatile("" ::: "memory");
}

// ---------- prep 1: fragment-ordered bf16 W_enc^T ----------
// Wf[((nt*16 + kb)*64 + lane)*8 + j] = bf16(W_enc[kb*32 + (lane>>4)*8 + j][nt*16 + (lane&15)])
__global__ void prep_w(const float* __restrict__ W_enc, unsigned short* __restrict__ Wf) {
  int idx = blockIdx.x * 256 + threadIdx.x;   // 0..32767
  int lane = idx & 63;
  int grp = idx >> 6;                         // nt*16 + kb
  int nt = grp >> 4, kb = grp & 15;
  int n = nt * 16 + (lane & 15);
  int k0 = kb * 32 + (lane >> 4) * 8;
  unsigned short* dst = Wf + idx * 8;
  #pragma unroll
  for (int j = 0; j < 8; ++j) {
    float f = W_enc[(k0 + j) * 512 + n];
    dst[j] = __builtin_bit_cast(unsigned short, (__bf16)f);
  }
}

// ---------- prep 2 (k-split x4): cpart[j][b][a] = partial dec_h@W_dec (+biases in j==0) ----------
__global__ void prep_c(const float* __restrict__ dec_h, const float* __restrict__ W_dec,
                       const float* __restrict__ b_dec, const float* __restrict__ b_enc,
                       float* __restrict__ cpart) {
  int b = blockIdx.x >> 2, j = blockIdx.x & 3;
  int a = threadIdx.x;                        // 512 threads
  const float* dh = dec_h + b * 512 + j * 128;
  const float* wd = W_dec + (j * 128) * 512 + a;
  float s = (j == 0) ? (b_dec[a] + b_enc[a]) : 0.f;
  #pragma unroll 8
  for (int k = 0; k < 128; ++k) s += dh[k] * wd[k * 512];
  cpart[j * 16384 + b * 512 + a] = s;
}

// ---------- main: 1024 thr / 16 waves / 1 block/CU. Waves 0-7 compute, 8-15 stage.
// ---------- Per window: ph1 = K-loop(i) || stage half0(i+1); ph2 = softmax+pw(i) || half1(i+1).
// ---------- Staging spans both phases -> HBM busy through the whole window. ----------
__global__ __launch_bounds__(1024, 4) void attn_main(
    const float* __restrict__ input, const unsigned short* __restrict__ Wf,
    const float* __restrict__ cpart, const float* __restrict__ w_att,
    float* __restrict__ att_out, float* __restrict__ m_out, float* __restrict__ pw_out) {
  __shared__ u32x4 A4[8192];                 // 2 x (64 rows x 512 bf16), XOR-swizzled (128 KB)
  __shared__ float c_lds[512];
  __shared__ float w_lds[512];
  __shared__ float red[8][64];               // epilogue partials

  char* Al = (char*)A4;
  const int tid = threadIdx.x;
  const int wave = tid >> 6, lane = tid & 63;
  const int l15 = lane & 15, l4 = lane >> 4;
  const int blk = blockIdx.x;                // 256 blocks, 1 per CU
  const int ci0 = blk * 8;                   // 8 chunks of 64 rows per block
  const int b = ci0 >> 6;                    // batch (all 8 chunks in same batch)
  const bool is_stage = wave >= 8;
  const int st = tid & 511;                  // stage thread id 0..511

  float4 g[4][2];                            // in-flight staging regs (32 VGPR) — small, short-lived

  // one half-tile (32 rows) of chunk ci: issue 8 global 16B loads, then cvt+swizzled LDS write
  auto STAGE_HALF = [&](int ci, int bufsel, int half) {
    const float* base = input + (long)ci * 32768;
    char* dst = Al + bufsel * 65536;
    #pragma unroll
    for (int j = 0; j < 4; ++j) {
      int ch = st + j * 512;                 // 0..2047 8-float units in this half
      int row = (ch >> 6) + half * 32, c32 = ch & 63;
      const float4* s4 = (const float4*)(base + row * 512 + c32 * 8);
      g[j][0] = s4[0];
      g[j][1] = s4[1];
    }
    #pragma unroll
    for (int j = 0; j < 4; ++j) {
      int ch = st + j * 512;
      int row = (ch >> 6) + half * 32, c32 = ch & 63;
      bf16x8 v;
      v[0] = (__bf16)g[j][0].x; v[1] = (__bf16)g[j][0].y;
      v[2] = (__bf16)g[j][0].z; v[3] = (__bf16)g[j][0].w;
      v[4] = (__bf16)g[j][1].x; v[5] = (__bf16)g[j][1].y;
      v[6] = (__bf16)g[j][1].z; v[7] = (__bf16)g[j][1].w;
      *(bf16x8*)(dst + row * 1024 + ((c32 * 16) ^ ((row & 7) << 4))) = v;
    }
  };

  // ---- prologue: compute waves fetch c/w; stage waves fill buf 0 with chunk 0 ----
  if (!is_stage) {
    c_lds[tid] = cpart[b * 512 + tid] + cpart[16384 + b * 512 + tid]
               + cpart[32768 + b * 512 + tid] + cpart[49152 + b * 512 + tid];
    w_lds[tid] = w_att[tid];
  } else {
    STAGE_HALF(ci0, 0, 0);
    STAGE_HALF(ci0, 0, 1);
  }
  barrier_lgkm();

  const bf16x8* Wfp = (const bf16x8*)Wf;

  for (int i = 0; i < 8; ++i) {
    const int ci = ci0 + i;
    const char* Ab = Al + (i & 1) * 65536;
    float p = 0.f;                           // per-lane softmax weight (row = lane)

    // ================= phase 1: K-loop || stage half 0 =================
    if (!is_stage) {
      f32x4 acc[4][4];
      #pragma unroll
      for (int mi = 0; mi < 4; ++mi)
        #pragma unroll
        for (int nj = 0; nj < 4; ++nj) {
          f32x4 z = {0.f, 0.f, 0.f, 0.f};
          acc[mi][nj] = z;
        }
      const bf16x8* wb = Wfp + (wave * 64) * 64 + lane;   // wave's 4 ntiles x 16 kb
      #pragma unroll 2
      for (int kb = 0; kb < 16; ++kb) {
        bf16x8 bv[4];
        #pragma unroll
        for (int nj = 0; nj < 4; ++nj)
          bv[nj] = wb[(nj * 16 + kb) * 64];
        __builtin_amdgcn_s_setprio(1);
        #pragma unroll
        for (int mi = 0; mi < 4; ++mi) {
          int row = mi * 16 + l15;
          bf16x8 afr = *(const bf16x8*)(Ab + row * 1024 + (((kb * 64) + l4 * 16) ^ ((row & 7) << 4)));
          #pragma unroll
          for (int nj = 0; nj < 4; ++nj)
            acc[mi][nj] = __builtin_amdgcn_mfma_f32_16x16x32_bf16(afr, bv[nj], acc[mi][nj], 0, 0, 0);
        }
        __builtin_amdgcn_s_setprio(0);
      }
      // epilogue: attp[row] = sum_n relu(enc_att + c[n]) * w[n]
      float attp[16];
      #pragma unroll
      for (int q = 0; q < 16; ++q) attp[q] = 0.f;
      #pragma unroll
      for (int nj = 0; nj < 4; ++nj) {
        int n = (wave * 4 + nj) * 16 + l15;
        float cc = c_lds[n], ww = w_lds[n];
        #pragma unroll
        for (int mi = 0; mi < 4; ++mi)
          #pragma unroll
          for (int r = 0; r < 4; ++r)
            attp[mi * 4 + r] += fmaxf(acc[mi][nj][r] + cc, 0.f) * ww;
      }
      #pragma unroll
      for (int off = 1; off < 16; off <<= 1)
        #pragma unroll
        for (int q = 0; q < 16; ++q)
          attp[q] += __shfl_xor(attp[q], off, 64);
      if (l15 == 0) {
        #pragma unroll
        for (int mi = 0; mi < 4; ++mi)
          #pragma unroll
          for (int r = 0; r < 4; ++r)
            red[wave][mi * 16 + l4 * 4 + r] = attp[mi * 4 + r];
      }
    } else if (i < 7) {
      STAGE_HALF(ci + 1, (i + 1) & 1, 0);
    }
    barrier_lgkm();

    // ================= phase 2: softmax + pw || stage half 1 =================
    if (!is_stage) {
      // redundant per-wave softmax over this chunk's 64 rows (row = lane)
      float av = 0.f;
      #pragma unroll
      for (int cw = 0; cw < 8; ++cw) av += red[cw][lane];
      float m = av;
      #pragma unroll
      for (int off = 32; off >= 1; off >>= 1) m = fmaxf(m, __shfl_xor(m, off, 64));
      p = expf(av - m);
      if (wave == 0) {
        att_out[b * 4096 + (ci & 63) * 64 + lane] = av;  // b_att omitted: cancels in softmax
        if (lane == 0) m_out[ci] = m;
      }
      // pw: one column per thread; broadcast LDS reads (adjacent lanes share the u32)
      const int ub = (tid >> 1) * 4;         // u32 byte offset within a row
      const bool hi = tid & 1;
      float pwa = 0.f;
      #pragma unroll 8
      for (int s = 0; s < 64; ++s) {
        float ps = __shfl(p, s, 64);
        unsigned int u = *(const unsigned int*)(Ab + s * 1024 + (ub ^ ((s & 7) << 4)));
        pwa += ps * (hi ? hi_bf(u) : lo_bf(u));
      }
      pw_out[ci * 512 + tid] = pwa;
    } else if (i < 7) {
      STAGE_HALF(ci + 1, (i + 1) & 1, 1);
    }
    barrier_lgkm();
  }
}

// ---------- finalize: per-batch global softmax + rescaled partial-sum reduction ----------
__global__ void finalize(const float* __restrict__ att, const float* __restrict__ m_blk,
                         const float* __restrict__ pw, float* __restrict__ out) {
  const int bg = blockIdx.x;                 // 128 blocks = 32 b x 4 groups
  const int b = bg >> 2, g = bg & 3;
  const int tid = threadIdx.x;               // 256
  const int wave = tid >> 6, lane = tid & 63;
  __shared__ float wred[4];
  __shared__ float zred[4];
  __shared__ float fac[64];

  float v[16];
  float mx = -3.4e38f;
  #pragma unroll
  for (int i = 0; i < 16; ++i) {
    v[i] = att[b * 4096 + i * 256 + tid];
    mx = fmaxf(mx, v[i]);
  }
  #pragma unroll
  for (int off = 32; off >= 1; off >>= 1) mx = fmaxf(mx, __shfl_xor(mx, off, 64));
  if (lane == 0) wred[wave] = mx;
  __syncthreads();
  mx = fmaxf(fmaxf(wred[0], wred[1]), fmaxf(wred[2], wred[3]));

  float z = 0.f;
  #pragma unroll
  for (int i = 0; i < 16; ++i) { v[i] = expf(v[i] - mx); z += v[i]; }
  #pragma unroll
  for (int off = 32; off >= 1; off >>= 1) z += __shfl_xor(z, off, 64);
  if (lane == 0) zred[wave] = z;
  __syncthreads();
  z = zred[0] + zred[1] + zred[2] + zred[3];
  float invZ = 1.f / z;

  #pragma unroll
  for (int i = 0; i < 4; ++i) {
    int ii = g * 4 + i;
    out[16384 + b * 4096 + ii * 256 + tid] = v[ii] * invZ;   // prob (this block's quarter)
  }

  if (tid < 64) fac[tid] = expf(m_blk[b * 64 + tid] - mx) * invZ;
  __syncthreads();

  int col = g * 128 + (tid >> 1);
  int h = tid & 1;
  float w0 = 0.f;
  #pragma unroll 8
  for (int s = h * 32; s < h * 32 + 32; ++s)
    w0 += fac[s] * pw[(b * 64 + s) * 512 + col];
  w0 += __shfl_xor(w0, 1, 64);
  if (h == 0) out[b * 512 + col] = w0;                       // weighted
}

extern "C" void kernel_launch(void* const* d_in, const int* in_sizes, int n_in,
                              void* d_out, int out_size, void* d_ws, size_t ws_size,
                              hipStream_t stream) {
  const float* input = (const float*)d_in[0];
  const float* dec_h = (const float*)d_in[1];
  const float* W_enc = (const float*)d_in[2];
  const float* b_enc = (const float*)d_in[3];
  const float* W_dec = (const float*)d_in[4];
  const float* b_dec = (const float*)d_in[5];
  const float* w_att = (const float*)d_in[6];
  // d_in[7] = b_att: constant shift of logits, cancels in softmax.
  float* out = (float*)d_out;

  char* ws = (char*)d_ws;
  unsigned short* Wf = (unsigned short*)(ws);           // 512 KB  fragment-ordered bf16 W_enc^T
  float* cpart = (float*)(ws + 524288);                 // 256 KB  dec_att partials [4][32][512]
  float* att   = (float*)(ws + 786432);                 // 512 KB  logits [32][4096]
  float* m_b   = (float*)(ws + 1310720);                // 8 KB    per-chunk max [2048]
  float* pw    = (float*)(ws + 1318912);                // 4 MB    partial weighted [2048][512]

  hipLaunchKernelGGL(prep_w, dim3(128), dim3(256), 0, stream, W_enc, Wf);
  hipLaunchKernelGGL(prep_c, dim3(128), dim3(512), 0, stream, dec_h, W_dec, b_dec, b_enc, cpart);
  hipLaunchKernelGGL(attn_main, dim3(256), dim3(1024), 0, stream, input, Wf, cpart, w_att, att, m_b, pw);
  hipLaunchKernelGGL(finalize, dim3(128), dim3(256), 0, stream, att, m_b, pw, out);
}

// Round 9
// 113.903 us; speedup vs baseline: 3.7608x; 1.1328x over previous
//
#include <hip/hip_runtime.h>
#include <hip/hip_bf16.h>

typedef __attribute__((ext_vector_type(4))) float f32x4;
typedef __attribute__((ext_vector_type(8))) __bf16 bf16x8;
typedef __attribute__((ext_vector_type(4))) unsigned int u32x4;

// B=32, S=4096, E=A=512.
// out = [weighted (32*512), prob (32*4096)] fp32, total 147456.

__device__ __forceinline__ float lo_bf(unsigned int u) {
  return __builtin_bit_cast(float, u << 16);
}
__device__ __forceinline__ float hi_bf(unsigned int u) {
  return __builtin_bit_cast(float, u & 0xffff0000u);
}

// Raw barrier: drain LDS ops only — vmcnt (global loads/stores) stays in flight.
__device__ __forceinline__ void barrier_lgkm() {
  asm volatile("s_waitcnt lgkmcnt(0)" ::: "memory");
  __builtin_amdgcn_s_barrier();
  asm volatile("" ::: "memory");
}

// ---------- prep 1: wave-contiguous A-fragment (W^T) layout ----------
// Wf[(((w*16 + kb)*4 + nt)*64 + lane)*8 + j] =
//   bf16(W_enc[kb*32 + (lane>>4)*8 + j][(w*4 + nt)*16 + (lane&15)])
// MFMA A-frag: i = lane&15 (n), k = (lane>>4)*8+j. Each wave's 64 KB is linear.
__global__ void prep_w(const float* __restrict__ W_enc, unsigned short* __restrict__ Wf) {
  int idx = blockIdx.x * 256 + threadIdx.x;   // 0..32767
  int lane = idx & 63;
  int g = idx >> 6;
  int nt = g & 3, kb = (g >> 2) & 15, w = g >> 6;
  int n = (w * 4 + nt) * 16 + (lane & 15);
  int k0 = kb * 32 + (lane >> 4) * 8;
  unsigned short* dst = Wf + idx * 8;
  #pragma unroll
  for (int j = 0; j < 8; ++j) {
    float f = W_enc[(k0 + j) * 512 + n];
    dst[j] = __builtin_bit_cast(unsigned short, (__bf16)f);
  }
}

// ---------- prep 2 (k-split x4): cpart[j][b][a] = partial dec_h@W_dec (+biases in j==0) ----------
__global__ void prep_c(const float* __restrict__ dec_h, const float* __restrict__ W_dec,
                       const float* __restrict__ b_dec, const float* __restrict__ b_enc,
                       float* __restrict__ cpart) {
  int b = blockIdx.x >> 2, j = blockIdx.x & 3;
  int a = threadIdx.x;                        // 512 threads
  const float* dh = dec_h + b * 512 + j * 128;
  const float* wd = W_dec + (j * 128) * 512 + a;
  float s = (j == 0) ? (b_dec[a] + b_enc[a]) : 0.f;
  #pragma unroll 8
  for (int k = 0; k < 128; ++k) s += dh[k] * wd[k * 512];
  cpart[j * 16384 + b * 512 + a] = s;
}

// ---------- main: 1024 thr / 16 waves / 1 block/CU. Waves 0-7 compute, 8-15 stage.
// ---------- Transposed MFMA (A=W rows=n, B=input cols=seq): in-lane n-reduction,
// ---------- 8 bpermutes/wave epilogue, conflict-free minimal-DS pw. ----------
__global__ __launch_bounds__(1024, 4) void attn_main(
    const float* __restrict__ input, const unsigned short* __restrict__ Wf,
    const float* __restrict__ cpart, const float* __restrict__ w_att,
    float* __restrict__ att_out, float* __restrict__ m_out, float* __restrict__ pw_out) {
  __shared__ u32x4 A4[8192];                 // 2 x (64 rows x 512 bf16), XOR-swizzled (128 KB)
  __shared__ float c_lds[512];
  __shared__ float w_lds[512];
  __shared__ float red[8][64];               // logit partials per wave
  __shared__ float red2[8 * 8 * 72];         // pw partials [w][q][72-padded lanes] (18.4 KB)

  char* Al = (char*)A4;
  const int tid = threadIdx.x;
  const int wave = tid >> 6, lane = tid & 63;
  const int l15 = lane & 15, l4 = lane >> 4;
  const int blk = blockIdx.x;                // 256 blocks, 1 per CU
  const int ci0 = blk * 8;                   // 8 chunks of 64 rows per block
  const int b = ci0 >> 6;                    // batch (all 8 chunks in same batch)
  const bool is_stage = wave >= 8;
  const int st_id = tid & 511;

  float4 g[4][2];                            // staging regs (32 VGPR, stage waves only)

  auto STAGE_HALF = [&](int ci, int bufsel, int half) {
    const float* base = input + (long)ci * 32768;
    char* dst = Al + bufsel * 65536;
    #pragma unroll
    for (int j = 0; j < 4; ++j) {
      int ch = st_id + j * 512;
      int row = (ch >> 6) + half * 32, c32 = ch & 63;
      const float4* s4 = (const float4*)(base + row * 512 + c32 * 8);
      g[j][0] = s4[0];
      g[j][1] = s4[1];
    }
    #pragma unroll
    for (int j = 0; j < 4; ++j) {
      int ch = st_id + j * 512;
      int row = (ch >> 6) + half * 32, c32 = ch & 63;
      bf16x8 v;
      v[0] = (__bf16)g[j][0].x; v[1] = (__bf16)g[j][0].y;
      v[2] = (__bf16)g[j][0].z; v[3] = (__bf16)g[j][0].w;
      v[4] = (__bf16)g[j][1].x; v[5] = (__bf16)g[j][1].y;
      v[6] = (__bf16)g[j][1].z; v[7] = (__bf16)g[j][1].w;
      *(bf16x8*)(dst + row * 1024 + ((c32 * 16) ^ ((row & 7) << 4))) = v;
    }
  };

  // ---- prologue ----
  if (!is_stage) {
    c_lds[tid] = cpart[b * 512 + tid] + cpart[16384 + b * 512 + tid]
               + cpart[32768 + b * 512 + tid] + cpart[49152 + b * 512 + tid];
    w_lds[tid] = w_att[tid];
  } else {
    STAGE_HALF(ci0, 0, 0);
    STAGE_HALF(ci0, 0, 1);
  }
  barrier_lgkm();

  const bf16x8* Wfp = (const bf16x8*)Wf;

  for (int i = 0; i < 8; ++i) {
    const int ci = ci0 + i;
    const char* Ab = Al + (i & 1) * 65536;

    // ============ phase 1: K-loop + epilogue  ||  stage half 0 ============
    if (!is_stage) {
      f32x4 acc[4][4];                       // [nt][st]: D rows=n, cols=seq
      #pragma unroll
      for (int nt = 0; nt < 4; ++nt)
        #pragma unroll
        for (int st = 0; st < 4; ++st) {
          f32x4 z = {0.f, 0.f, 0.f, 0.f};
          acc[nt][st] = z;
        }
      const bf16x8* wb = Wfp + (wave * 64) * 64 + lane;   // wave's 64KB linear region
      #pragma unroll 2
      for (int kb = 0; kb < 16; ++kb) {
        bf16x8 av4[4];
        #pragma unroll
        for (int nt = 0; nt < 4; ++nt)
          av4[nt] = wb[(kb * 4 + nt) * 64];  // 4KB contiguous per kb
        __builtin_amdgcn_s_setprio(1);
        #pragma unroll
        for (int st = 0; st < 4; ++st) {
          int row = st * 16 + l15;
          bf16x8 xf = *(const bf16x8*)(Ab + row * 1024 + (((kb * 64) + l4 * 16) ^ ((row & 7) << 4)));
          #pragma unroll
          for (int nt = 0; nt < 4; ++nt)
            acc[nt][st] = __builtin_amdgcn_mfma_f32_16x16x32_bf16(av4[nt], xf, acc[nt][st], 0, 0, 0);
        }
        __builtin_amdgcn_s_setprio(0);
      }
      // epilogue: att partial over this wave's 64 n; n-sum is in-lane over (nt,r), cross-lane over l4 only
      float attp[4] = {0.f, 0.f, 0.f, 0.f};
      #pragma unroll
      for (int nt = 0; nt < 4; ++nt) {
        #pragma unroll
        for (int r = 0; r < 4; ++r) {
          int n = (wave * 4 + nt) * 16 + l4 * 4 + r;
          float cc = c_lds[n], ww = w_lds[n];
          #pragma unroll
          for (int st = 0; st < 4; ++st)
            attp[st] += fmaxf(acc[nt][st][r] + cc, 0.f) * ww;
        }
      }
      #pragma unroll
      for (int st = 0; st < 4; ++st) {
        attp[st] += __shfl_xor(attp[st], 16, 64);
        attp[st] += __shfl_xor(attp[st], 32, 64);
      }
      if (l4 == 0) {
        #pragma unroll
        for (int st = 0; st < 4; ++st)
          red[wave][st * 16 + l15] = attp[st];
      }
    } else if (i < 7) {
      STAGE_HALF(ci + 1, (i + 1) & 1, 0);
    }
    barrier_lgkm();

    // ============ phase 2a: softmax + pw partials  ||  stage half 1 ============
    if (!is_stage) {
      float av = 0.f;
      #pragma unroll
      for (int cw = 0; cw < 8; ++cw) av += red[cw][lane];
      float m = av;
      #pragma unroll
      for (int off = 32; off >= 1; off >>= 1) m = fmaxf(m, __shfl_xor(m, off, 64));
      float p = expf(av - m);                // row = lane
      if (wave == 0) {
        att_out[b * 4096 + (ci & 63) * 64 + lane] = av;  // b_att omitted: cancels in softmax
        if (lane == 0) m_out[ci] = m;
      }
      // pw: wave w owns s-rows w*8..w*8+7; lane reads full permuted row slice (conflict-free)
      float acc8[8] = {0.f, 0.f, 0.f, 0.f, 0.f, 0.f, 0.f, 0.f};
      #pragma unroll
      for (int j = 0; j < 8; ++j) {
        int s = wave * 8 + j;
        float ps = __shfl(p, s, 64);
        u32x4 u = *(const u32x4*)(Ab + s * 1024 + ((lane * 16) ^ ((s & 7) << 4)));
        acc8[0] += ps * lo_bf(u[0]); acc8[1] += ps * hi_bf(u[0]);
        acc8[2] += ps * lo_bf(u[1]); acc8[3] += ps * hi_bf(u[1]);
        acc8[4] += ps * lo_bf(u[2]); acc8[5] += ps * hi_bf(u[2]);
        acc8[6] += ps * lo_bf(u[3]); acc8[7] += ps * hi_bf(u[3]);
      }
      #pragma unroll
      for (int q = 0; q < 8; ++q)
        red2[(wave * 8 + q) * 72 + lane] = acc8[q];      // cols lane*8+q, s-oct = wave
    } else if (i < 7) {
      STAGE_HALF(ci + 1, (i + 1) & 1, 1);
    }
    barrier_lgkm();

    // ============ phase 2b: combine pw partials across waves, store ============
    if (tid < 512) {
      int lw = tid >> 3, q = tid & 7;        // col = lw*8 + q
      float s = 0.f;
      #pragma unroll
      for (int w = 0; w < 8; ++w) s += red2[(w * 8 + q) * 72 + lw];
      pw_out[ci * 512 + lw * 8 + q] = s;
    }
    barrier_lgkm();
  }
}

// ---------- finalize: per-batch global softmax + rescaled partial-sum reduction ----------
__global__ void finalize(const float* __restrict__ att, const float* __restrict__ m_blk,
                         const float* __restrict__ pw, float* __restrict__ out) {
  const int bg = blockIdx.x;                 // 128 blocks = 32 b x 4 groups
  const int b = bg >> 2, g = bg & 3;
  const int tid = threadIdx.x;               // 256
  const int wave = tid >> 6, lane = tid & 63;
  __shared__ float wred[4];
  __shared__ float zred[4];
  __shared__ float fac[64];

  float v[16];
  float mx = -3.4e38f;
  #pragma unroll
  for (int i = 0; i < 16; ++i) {
    v[i] = att[b * 4096 + i * 256 + tid];
    mx = fmaxf(mx, v[i]);
  }
  #pragma unroll
  for (int off = 32; off >= 1; off >>= 1) mx = fmaxf(mx, __shfl_xor(mx, off, 64));
  if (lane == 0) wred[wave] = mx;
  __syncthreads();
  mx = fmaxf(fmaxf(wred[0], wred[1]), fmaxf(wred[2], wred[3]));

  float z = 0.f;
  #pragma unroll
  for (int i = 0; i < 16; ++i) { v[i] = expf(v[i] - mx); z += v[i]; }
  #pragma unroll
  for (int off = 32; off >= 1; off >>= 1) z += __shfl_xor(z, off, 64);
  if (lane == 0) zred[wave] = z;
  __syncthreads();
  z = zred[0] + zred[1] + zred[2] + zred[3];
  float invZ = 1.f / z;

  #pragma unroll
  for (int i = 0; i < 4; ++i) {
    int ii = g * 4 + i;
    out[16384 + b * 4096 + ii * 256 + tid] = v[ii] * invZ;   // prob (this block's quarter)
  }

  if (tid < 64) fac[tid] = expf(m_blk[b * 64 + tid] - mx) * invZ;
  __syncthreads();

  int col = g * 128 + (tid >> 1);
  int h = tid & 1;
  float w0 = 0.f;
  #pragma unroll 8
  for (int s = h * 32; s < h * 32 + 32; ++s)
    w0 += fac[s] * pw[(b * 64 + s) * 512 + col];
  w0 += __shfl_xor(w0, 1, 64);
  if (h == 0) out[b * 512 + col] = w0;                       // weighted
}

extern "C" void kernel_launch(void* const* d_in, const int* in_sizes, int n_in,
                              void* d_out, int out_size, void* d_ws, size_t ws_size,
                              hipStream_t stream) {
  const float* input = (const float*)d_in[0];
  const float* dec_h = (const float*)d_in[1];
  const float* W_enc = (const float*)d_in[2];
  const float* b_enc = (const float*)d_in[3];
  const float* W_dec = (const float*)d_in[4];
  const float* b_dec = (const float*)d_in[5];
  const float* w_att = (const float*)d_in[6];
  // d_in[7] = b_att: constant shift of logits, cancels in softmax.
  float* out = (float*)d_out;

  char* ws = (char*)d_ws;
  unsigned short* Wf = (unsigned short*)(ws);           // 512 KB  A-fragment-ordered bf16 W_enc^T
  float* cpart = (float*)(ws + 524288);                 // 256 KB  dec_att partials [4][32][512]
  float* att   = (float*)(ws + 786432);                 // 512 KB  logits [32][4096]
  float* m_b   = (float*)(ws + 1310720);                // 8 KB    per-chunk max [2048]
  float* pw    = (float*)(ws + 1318912);                // 4 MB    partial weighted [2048][512]

  hipLaunchKernelGGL(prep_w, dim3(128), dim3(256), 0, stream, W_enc, Wf);
  hipLaunchKernelGGL(prep_c, dim3(128), dim3(512), 0, stream, dec_h, W_dec, b_dec, b_enc, cpart);
  hipLaunchKernelGGL(attn_main, dim3(256), dim3(1024), 0, stream, input, Wf, cpart, w_att, att, m_b, pw);
  hipLaunchKernelGGL(finalize, dim3(128), dim3(256), 0, stream, att, m_b, pw, out);
}